// Round 10
// baseline (102.608 us; speedup 1.0000x reference)
//
#include <hip/hip_runtime.h>
#include <hip/hip_bf16.h>

#define TT 8192
#define DIN 512
#define DQK 64

typedef __attribute__((ext_vector_type(8))) short short8;
typedef __attribute__((ext_vector_type(4))) float f32x4;

static __device__ __forceinline__ unsigned pack_bf16(float a, float b) {
    __hip_bfloat16 ha = __float2bfloat16(a);
    __hip_bfloat16 hb = __float2bfloat16(b);
    return (unsigned)(*(unsigned short*)&ha) | ((unsigned)(*(unsigned short*)&hb) << 16);
}

static __device__ __forceinline__ short8 cvt8(const float* p) {
    short tmp[8];
    #pragma unroll
    for (int j = 0; j < 8; ++j) {
        __hip_bfloat16 h = __float2bfloat16(p[j]);
        tmp[j] = *(short*)&h;
    }
    return *(short8*)tmp;
}

// ---------------- Kernel 0: fused zero(d_out) + wconv (W -> WT bf16) ----------------
__global__ __launch_bounds__(256) void init_kernel(
    const float* __restrict__ Wq, const float* __restrict__ Wk, const float* __restrict__ Wv,
    __hip_bfloat16* __restrict__ wtb, float* __restrict__ out, int n4)
{
    __shared__ float tile[64][65];
    const int b = blockIdx.x;
    const int tid = threadIdx.x;

    if (b >= 24) {
        const int nthr = 24 * 256;
        for (int i = (b - 24) * 256 + tid; i < n4; i += nthr)
            ((f32x4*)out)[i] = (f32x4){0.f, 0.f, 0.f, 0.f};
        return;
    }

    const int m = b >> 3;
    const float* W = m == 0 ? Wq : (m == 1 ? Wk : Wv);
    const int k0 = (b & 7) * 64;

    {
        const int col4 = (tid & 15) * 4;
        #pragma unroll
        for (int it = 0; it < 4; ++it) {
            const int row = (tid >> 4) + it * 16;
            float4 v = *(const float4*)&W[(size_t)(k0 + row) * DQK + col4];
            tile[row][col4 + 0] = v.x; tile[row][col4 + 1] = v.y;
            tile[row][col4 + 2] = v.z; tile[row][col4 + 3] = v.w;
        }
    }
    __syncthreads();
    {
        const int d = tid >> 2;
        const int kc = (tid & 3) * 16;
        short tmp[16];
        #pragma unroll
        for (int j = 0; j < 16; ++j) {
            __hip_bfloat16 h = __float2bfloat16(tile[kc + j][d]);
            tmp[j] = *(short*)&h;
        }
        short* dst = (short*)wtb + ((size_t)m * 64 + d) * DIN + k0 + kc;
        *(short8*)dst       = *(short8*)&tmp[0];
        *(short8*)(dst + 8) = *(short8*)&tmp[8];
    }
}

// ---------------- Kernel 1: barrier-free 1-wave MFMA projections (512 blocks) ----------------
__global__ __launch_bounds__(64) void proj_kernel(
    const float* __restrict__ x,
    const __hip_bfloat16* __restrict__ wtb,
    __hip_bfloat16* __restrict__ qb, __hip_bfloat16* __restrict__ kb,
    __hip_bfloat16* __restrict__ vt)
{
    __shared__ float tile[16][65];
    const int rowBase = blockIdx.x * 16;
    const int lane = threadIdx.x;
    const int lo = lane & 15, hi = lane >> 4;

    f32x4 acc[3][4];
    #pragma unroll
    for (int m = 0; m < 3; ++m)
        #pragma unroll
        for (int cf = 0; cf < 4; ++cf) acc[m][cf] = (f32x4){0.f, 0.f, 0.f, 0.f};

    const float* xp0 = x + (size_t)(rowBase + lo) * DIN + hi * 8;
    const short* wb0 = (const short*)wtb + (size_t)lo * DIN + hi * 8;

    for (int kk = 0; kk < DIN; kk += 64) {
        float xa[8], xb[8];
        *(float4*)&xa[0] = *(const float4*)(xp0 + kk);
        *(float4*)&xa[4] = *(const float4*)(xp0 + kk + 4);
        *(float4*)&xb[0] = *(const float4*)(xp0 + kk + 32);
        *(float4*)&xb[4] = *(const float4*)(xp0 + kk + 36);
        short8 af0 = cvt8(xa), af1 = cvt8(xb);
        #pragma unroll
        for (int m = 0; m < 3; ++m) {
            #pragma unroll
            for (int cf = 0; cf < 4; ++cf) {
                const short* wp = wb0 + ((size_t)m * 64 + cf * 16) * DIN + kk;
                short8 b0 = *(const short8*)wp;
                short8 b1 = *(const short8*)(wp + 32);
                acc[m][cf] = __builtin_amdgcn_mfma_f32_16x16x32_bf16(af0, b0, acc[m][cf], 0, 0, 0);
                acc[m][cf] = __builtin_amdgcn_mfma_f32_16x16x32_bf16(af1, b1, acc[m][cf], 0, 0, 0);
            }
        }
    }

    // q,k: row-major stores
    #pragma unroll
    for (int m = 0; m < 2; ++m) {
        __hip_bfloat16* o = (m == 0) ? qb : kb;
        #pragma unroll
        for (int cf = 0; cf < 4; ++cf)
            #pragma unroll
            for (int r = 0; r < 4; ++r)
                o[(size_t)(rowBase + 4 * hi + r) * DQK + cf * 16 + lo] =
                    __float2bfloat16(acc[m][cf][r]);
    }

    // v: transpose via LDS, vectorized short8 stores to vt[d][t]
    #pragma unroll
    for (int cf = 0; cf < 4; ++cf)
        #pragma unroll
        for (int r = 0; r < 4; ++r)
            tile[4 * hi + r][cf * 16 + lo] = acc[2][cf][r];
    __syncthreads();
    {
        const int d = lane;
        short tmp[16];
        #pragma unroll
        for (int j = 0; j < 16; ++j) {
            __hip_bfloat16 h = __float2bfloat16(tile[j][d]);
            tmp[j] = *(short*)&h;
        }
        short* dst = (short*)vt + (size_t)d * TT + rowBase;
        *(short8*)dst       = *(short8*)&tmp[0];
        *(short8*)(dst + 8) = *(short8*)&tmp[8];
    }
}

// ---------------- Kernel 2: R4 schedule + swapped-QK S/l layout ----------------
#define TM 128       // t rows per block (8 waves x 16)
#define TS 64        // s per step
#define SCHUNK 256   // s range per block (grid.y)
#define LP 72        // padded LDS row stride in shorts (144 B)

__global__ __launch_bounds__(512) void attn_kernel(
    const __hip_bfloat16* __restrict__ qb,
    const __hip_bfloat16* __restrict__ kb,
    const __hip_bfloat16* __restrict__ vt,
    const float* __restrict__ l,
    float* __restrict__ out)
{
    __shared__ short K_lds[TS][LP];      // K[s][k]
    __shared__ short V_lds[DQK][LP];     // Vt[d][s_local]
    __shared__ short S_lds[8][16][LP];   // wave-private S[t_loc][s_local]

    const int t0 = blockIdx.x * TM;
    const int sStart = blockIdx.y * SCHUNK;
    if (sStart >= t0 + TM) return;
    const int sEnd = min(sStart + SCHUNK, t0 + TM);

    const int tid = threadIdx.x;
    const int lane = tid & 63;
    const int w = tid >> 6;
    const int lo = lane & 15, hi = lane >> 4;
    const int trow = t0 + w * 16;
    const int tmine = trow + lo;        // swapped layout: this lane's t-row
    const bool waveActive = (sStart <= trow + 15);

    short8 qf0, qf1;
    {
        const short* qp = (const short*)qb + (size_t)tmine * DQK;
        qf0 = *(const short8*)(qp + hi * 8);
        qf1 = *(const short8*)(qp + 32 + hi * 8);
    }

    f32x4 acc_o[4];
    #pragma unroll
    for (int i = 0; i < 4; ++i) acc_o[i] = (f32x4){0.f, 0.f, 0.f, 0.f};

    const float* lrow = l + (size_t)tmine * TT;
    const int sb = 4 * hi;              // lane's s-subbase within each 16-block

    // l register double-buffer: lvC[sub] covers s = s0 + sub*16 + sb + [0..3]
    f32x4 lvC[4];
    f32x4 lvN[4];
    if (waveActive) {
        #pragma unroll
        for (int sub = 0; sub < 4; ++sub) {
            f32x4 raw = __builtin_nontemporal_load(
                (const f32x4*)(lrow + sStart + sub * 16 + sb));
            if (sStart + 63 <= trow) {
                lvC[sub] = raw;
            } else {
                #pragma unroll
                for (int r = 0; r < 4; ++r)
                    lvC[sub][r] = (sStart + sub * 16 + sb + r <= tmine) ? raw[r] : 0.f;
            }
        }
    }

    for (int s0 = sStart; s0 < sEnd; s0 += TS) {
        // stage K (64x64) and Vt (64x64): one short8 per thread per matrix
        {
            const int row = tid >> 3;
            const int c8 = (tid & 7) * 8;
            *(short8*)&K_lds[row][c8] =
                *(const short8*)((const short*)kb + (size_t)(s0 + row) * DQK + c8);
            *(short8*)&V_lds[row][c8] =
                *(const short8*)((const short*)vt + (size_t)row * TT + s0 + c8);
        }
        __syncthreads();

        const bool active = (s0 <= trow + 15);
        const int sN = s0 + TS;
        const bool act_next = (sN < sEnd) && (sN <= trow + 15);

        // prefetch next step's l slice (4 fat f32x4 loads; fly during MFMA)
        if (act_next) {
            if (sN + 63 <= trow) {
                #pragma unroll
                for (int sub = 0; sub < 4; ++sub)
                    lvN[sub] = __builtin_nontemporal_load(
                        (const f32x4*)(lrow + sN + sub * 16 + sb));
            } else {
                #pragma unroll
                for (int sub = 0; sub < 4; ++sub) {
                    f32x4 raw = __builtin_nontemporal_load(
                        (const f32x4*)(lrow + sN + sub * 16 + sb));
                    #pragma unroll
                    for (int r = 0; r < 4; ++r)
                        lvN[sub][r] = (sN + sub * 16 + sb + r <= tmine) ? raw[r] : 0.f;
                }
            }
        }

        if (active) {
            // swapped QK^T: C[s][t] with t = lo (fixed), s = s0+16sub+sb+r
            #pragma unroll
            for (int sub = 0; sub < 4; ++sub) {
                f32x4 acc = (f32x4){0.f, 0.f, 0.f, 0.f};
                short8 b0 = *(short8*)&K_lds[sub * 16 + lo][hi * 8];
                short8 b1 = *(short8*)&K_lds[sub * 16 + lo][32 + hi * 8];
                acc = __builtin_amdgcn_mfma_f32_16x16x32_bf16(b0, qf0, acc, 0, 0, 0);
                acc = __builtin_amdgcn_mfma_f32_16x16x32_bf16(b1, qf1, acc, 0, 0, 0);
                // 4 s-contiguous values -> one b64 write
                unsigned d0 = pack_bf16(acc[0] * lvC[sub][0], acc[1] * lvC[sub][1]);
                unsigned d1 = pack_bf16(acc[2] * lvC[sub][2], acc[3] * lvC[sub][3]);
                unsigned long long v = (unsigned long long)d0 |
                                       ((unsigned long long)d1 << 32);
                *(unsigned long long*)&S_lds[w][lo][sub * 16 + sb] = v;
            }
            // PV: A-frag b128 reads unchanged (row t=lo, k=s=hi*8+j)
            short8 a0 = *(short8*)&S_lds[w][lo][hi * 8];
            short8 a1 = *(short8*)&S_lds[w][lo][32 + hi * 8];
            #pragma unroll
            for (int ds = 0; ds < 4; ++ds) {
                short8 b0 = *(short8*)&V_lds[ds * 16 + lo][hi * 8];
                short8 b1 = *(short8*)&V_lds[ds * 16 + lo][32 + hi * 8];
                acc_o[ds] = __builtin_amdgcn_mfma_f32_16x16x32_bf16(a0, b0, acc_o[ds], 0, 0, 0);
                acc_o[ds] = __builtin_amdgcn_mfma_f32_16x16x32_bf16(a1, b1, acc_o[ds], 0, 0, 0);
            }
        }
        __syncthreads();

        #pragma unroll
        for (int sub = 0; sub < 4; ++sub)
            lvC[sub] = lvN[sub];
    }

    // epilogue: C[t=4hi+r][d=ds*16+lo] (unchanged layout)
    if (waveActive) {
        #pragma unroll
        for (int ds = 0; ds < 4; ++ds) {
            #pragma unroll
            for (int r = 0; r < 4; ++r) {
                const int tg = trow + 4 * hi + r;
                atomicAdd(&out[(size_t)tg * DQK + ds * 16 + lo], acc_o[ds][r]);
            }
        }
    }
}

extern "C" void kernel_launch(void* const* d_in, const int* in_sizes, int n_in,
                              void* d_out, int out_size, void* d_ws, size_t ws_size,
                              hipStream_t stream) {
    const float* x  = (const float*)d_in[0];
    const float* Wq = (const float*)d_in[1];
    const float* Wk = (const float*)d_in[2];
    const float* Wv = (const float*)d_in[3];
    const float* l  = (const float*)d_in[4];
    float* out = (float*)d_out;

    __hip_bfloat16* qb  = (__hip_bfloat16*)d_ws;
    __hip_bfloat16* kb  = qb + (size_t)TT * DQK;
    __hip_bfloat16* vt  = kb + (size_t)TT * DQK;
    __hip_bfloat16* wtb = vt + (size_t)TT * DQK;   // [3][64][512]

    init_kernel<<<48, 256, 0, stream>>>(Wq, Wk, Wv, wtb, out, out_size / 4);
    proj_kernel<<<TT / 16, 64, 0, stream>>>(x, wtb, qb, kb, vt);
    attn_kernel<<<dim3(TT / TM, TT / SCHUNK), 512, 0, stream>>>(qb, kb, vt, l, out);
}

// Round 11
// 79.127 us; speedup vs baseline: 1.2967x; 1.2967x over previous
//
#include <hip/hip_runtime.h>
#include <hip/hip_bf16.h>

#define TT 8192
#define DIN 512
#define DQK 64

typedef __attribute__((ext_vector_type(8))) short short8;
typedef __attribute__((ext_vector_type(4))) float f32x4;

static __device__ __forceinline__ unsigned pack_bf16(float a, float b) {
    __hip_bfloat16 ha = __float2bfloat16(a);
    __hip_bfloat16 hb = __float2bfloat16(b);
    return (unsigned)(*(unsigned short*)&ha) | ((unsigned)(*(unsigned short*)&hb) << 16);
}

// ---------------- Kernel 0: fused zero(d_out) + wconv (W -> WT bf16) ----------------
__global__ __launch_bounds__(256) void init_kernel(
    const float* __restrict__ Wq, const float* __restrict__ Wk, const float* __restrict__ Wv,
    __hip_bfloat16* __restrict__ wtb, float* __restrict__ out, int n4)
{
    __shared__ float tile[64][65];
    const int b = blockIdx.x;
    const int tid = threadIdx.x;

    if (b >= 24) {
        const int nthr = 24 * 256;
        for (int i = (b - 24) * 256 + tid; i < n4; i += nthr)
            ((f32x4*)out)[i] = (f32x4){0.f, 0.f, 0.f, 0.f};
        return;
    }

    const int m = b >> 3;
    const float* W = m == 0 ? Wq : (m == 1 ? Wk : Wv);
    const int k0 = (b & 7) * 64;

    {
        const int col4 = (tid & 15) * 4;
        #pragma unroll
        for (int it = 0; it < 4; ++it) {
            const int row = (tid >> 4) + it * 16;
            float4 v = *(const float4*)&W[(size_t)(k0 + row) * DQK + col4];
            tile[row][col4 + 0] = v.x; tile[row][col4 + 1] = v.y;
            tile[row][col4 + 2] = v.z; tile[row][col4 + 3] = v.w;
        }
    }
    __syncthreads();
    {
        const int d = tid >> 2;
        const int kc = (tid & 3) * 16;
        short tmp[16];
        #pragma unroll
        for (int j = 0; j < 16; ++j) {
            __hip_bfloat16 h = __float2bfloat16(tile[kc + j][d]);
            tmp[j] = *(short*)&h;
        }
        short* dst = (short*)wtb + ((size_t)m * 64 + d) * DIN + k0 + kc;
        *(short8*)dst       = *(short8*)&tmp[0];
        *(short8*)(dst + 8) = *(short8*)&tmp[8];
    }
}

// ---------------- Kernel 1: MFMA projections (R4 proven version) ----------------
#define PP 72

__global__ __launch_bounds__(256) void proj_kernel(
    const float* __restrict__ x,
    const __hip_bfloat16* __restrict__ wtb,
    __hip_bfloat16* __restrict__ qb, __hip_bfloat16* __restrict__ kb,
    __hip_bfloat16* __restrict__ vt)
{
    __shared__ short xb[64][PP];        // x tile [row][k]
    __shared__ short wb[3][64][PP];     // W^T tiles [m][col(d)][k]

    const int rowBase = blockIdx.x * 64;
    const int tid = threadIdx.x;
    const int lane = tid & 63;
    const int w = tid >> 6;
    const int lo = lane & 15, hi = lane >> 4;

    f32x4 acc[3][4];
    #pragma unroll
    for (int m = 0; m < 3; ++m)
        #pragma unroll
        for (int cf = 0; cf < 4; ++cf) acc[m][cf] = (f32x4){0.f, 0.f, 0.f, 0.f};

    for (int kk = 0; kk < DIN; kk += 64) {
        // stage x 64x64 -> bf16 (vectorized)
        {
            const int r = tid >> 2;
            const int c0 = (tid & 3) * 16;
            const float* xp = x + (size_t)(rowBase + r) * DIN + kk + c0;
            short tmp[16];
            #pragma unroll
            for (int j = 0; j < 16; j += 4) {
                float4 v = *(const float4*)(xp + j);
                __hip_bfloat16 h0 = __float2bfloat16(v.x);
                __hip_bfloat16 h1 = __float2bfloat16(v.y);
                __hip_bfloat16 h2 = __float2bfloat16(v.z);
                __hip_bfloat16 h3 = __float2bfloat16(v.w);
                tmp[j + 0] = *(short*)&h0; tmp[j + 1] = *(short*)&h1;
                tmp[j + 2] = *(short*)&h2; tmp[j + 3] = *(short*)&h3;
            }
            *(short8*)&xb[r][c0]     = *(short8*)&tmp[0];
            *(short8*)&xb[r][c0 + 8] = *(short8*)&tmp[8];
        }
        // stage W^T (already bf16, vector copy)
        {
            const int d = tid >> 2;
            const int kc = (tid & 3) * 16;
            #pragma unroll
            for (int m = 0; m < 3; ++m) {
                const short* src = (const short*)wtb + ((size_t)m * 64 + d) * DIN + kk + kc;
                *(short8*)&wb[m][d][kc]     = *(const short8*)src;
                *(short8*)&wb[m][d][kc + 8] = *(const short8*)(src + 8);
            }
        }
        __syncthreads();

        short8 a0 = *(short8*)&xb[w * 16 + lo][hi * 8];
        short8 a1 = *(short8*)&xb[w * 16 + lo][32 + hi * 8];
        #pragma unroll
        for (int m = 0; m < 3; ++m) {
            #pragma unroll
            for (int cf = 0; cf < 4; ++cf) {
                short8 b0 = *(short8*)&wb[m][cf * 16 + lo][hi * 8];
                short8 b1 = *(short8*)&wb[m][cf * 16 + lo][32 + hi * 8];
                acc[m][cf] = __builtin_amdgcn_mfma_f32_16x16x32_bf16(a0, b0, acc[m][cf], 0, 0, 0);
                acc[m][cf] = __builtin_amdgcn_mfma_f32_16x16x32_bf16(a1, b1, acc[m][cf], 0, 0, 0);
            }
        }
        __syncthreads();
    }

    #pragma unroll
    for (int cf = 0; cf < 4; ++cf) {
        #pragma unroll
        for (int r = 0; r < 4; ++r) {
            const int tg = rowBase + w * 16 + hi * 4 + r;
            const int d  = cf * 16 + lo;
            __hip_bfloat16 hq = __float2bfloat16(acc[0][cf][r]);
            __hip_bfloat16 hk = __float2bfloat16(acc[1][cf][r]);
            __hip_bfloat16 hv = __float2bfloat16(acc[2][cf][r]);
            qb[(size_t)tg * DQK + d] = hq;
            kb[(size_t)tg * DQK + d] = hk;
            vt[(size_t)d * TT + tg]  = hv;
        }
    }
}

// ---------------- Kernel 2: R4 schedule + swapped-QK S/l layout ----------------
#define TM 128       // t rows per block (8 waves x 16)
#define TS 64        // s per step
#define SCHUNK 256   // s range per block (grid.y)
#define LP 72        // padded LDS row stride in shorts (144 B)

__global__ __launch_bounds__(512) void attn_kernel(
    const __hip_bfloat16* __restrict__ qb,
    const __hip_bfloat16* __restrict__ kb,
    const __hip_bfloat16* __restrict__ vt,
    const float* __restrict__ l,
    float* __restrict__ out)
{
    __shared__ short K_lds[TS][LP];      // K[s][k]
    __shared__ short V_lds[DQK][LP];     // Vt[d][s_local]
    __shared__ short S_lds[8][16][LP];   // wave-private S[t_loc][s_local]

    const int t0 = blockIdx.x * TM;
    const int sStart = blockIdx.y * SCHUNK;
    if (sStart >= t0 + TM) return;
    const int sEnd = min(sStart + SCHUNK, t0 + TM);

    const int tid = threadIdx.x;
    const int lane = tid & 63;
    const int w = tid >> 6;
    const int lo = lane & 15, hi = lane >> 4;
    const int trow = t0 + w * 16;
    const int tmine = trow + lo;        // swapped layout: this lane's t-row
    const bool waveActive = (sStart <= trow + 15);

    short8 qf0, qf1;
    {
        const short* qp = (const short*)qb + (size_t)tmine * DQK;
        qf0 = *(const short8*)(qp + hi * 8);
        qf1 = *(const short8*)(qp + 32 + hi * 8);
    }

    f32x4 acc_o[4];
    #pragma unroll
    for (int i = 0; i < 4; ++i) acc_o[i] = (f32x4){0.f, 0.f, 0.f, 0.f};

    const float* lrow = l + (size_t)tmine * TT;
    const int sb = 4 * hi;              // lane's s-subbase within each 16-block

    // l register double-buffer: lvC[sub] covers s = s0 + sub*16 + sb + [0..3]
    f32x4 lvC[4];
    f32x4 lvN[4];
    if (waveActive) {
        #pragma unroll
        for (int sub = 0; sub < 4; ++sub) {
            f32x4 raw = __builtin_nontemporal_load(
                (const f32x4*)(lrow + sStart + sub * 16 + sb));
            if (sStart + 63 <= trow) {
                lvC[sub] = raw;
            } else {
                #pragma unroll
                for (int r = 0; r < 4; ++r)
                    lvC[sub][r] = (sStart + sub * 16 + sb + r <= tmine) ? raw[r] : 0.f;
            }
        }
    }

    for (int s0 = sStart; s0 < sEnd; s0 += TS) {
        // stage K (64x64) and Vt (64x64): one short8 per thread per matrix
        {
            const int row = tid >> 3;
            const int c8 = (tid & 7) * 8;
            *(short8*)&K_lds[row][c8] =
                *(const short8*)((const short*)kb + (size_t)(s0 + row) * DQK + c8);
            *(short8*)&V_lds[row][c8] =
                *(const short8*)((const short*)vt + (size_t)row * TT + s0 + c8);
        }
        __syncthreads();

        const bool active = (s0 <= trow + 15);
        const int sN = s0 + TS;
        const bool act_next = (sN < sEnd) && (sN <= trow + 15);

        // prefetch next step's l slice (4 fat f32x4 loads; fly during MFMA)
        if (act_next) {
            if (sN + 63 <= trow) {
                #pragma unroll
                for (int sub = 0; sub < 4; ++sub)
                    lvN[sub] = __builtin_nontemporal_load(
                        (const f32x4*)(lrow + sN + sub * 16 + sb));
            } else {
                #pragma unroll
                for (int sub = 0; sub < 4; ++sub) {
                    f32x4 raw = __builtin_nontemporal_load(
                        (const f32x4*)(lrow + sN + sub * 16 + sb));
                    #pragma unroll
                    for (int r = 0; r < 4; ++r)
                        lvN[sub][r] = (sN + sub * 16 + sb + r <= tmine) ? raw[r] : 0.f;
                }
            }
        }

        if (active) {
            // swapped QK^T: C[s][t] with t = lo (fixed), s = s0+16sub+sb+r
            #pragma unroll
            for (int sub = 0; sub < 4; ++sub) {
                f32x4 acc = (f32x4){0.f, 0.f, 0.f, 0.f};
                short8 b0 = *(short8*)&K_lds[sub * 16 + lo][hi * 8];
                short8 b1 = *(short8*)&K_lds[sub * 16 + lo][32 + hi * 8];
                acc = __builtin_amdgcn_mfma_f32_16x16x32_bf16(b0, qf0, acc, 0, 0, 0);
                acc = __builtin_amdgcn_mfma_f32_16x16x32_bf16(b1, qf1, acc, 0, 0, 0);
                // 4 s-contiguous values -> one b64 write
                unsigned d0 = pack_bf16(acc[0] * lvC[sub][0], acc[1] * lvC[sub][1]);
                unsigned d1 = pack_bf16(acc[2] * lvC[sub][2], acc[3] * lvC[sub][3]);
                unsigned long long v = (unsigned long long)d0 |
                                       ((unsigned long long)d1 << 32);
                *(unsigned long long*)&S_lds[w][lo][sub * 16 + sb] = v;
            }
            // PV: A-frag b128 reads (row t=lo, k=s=hi*8+j)
            short8 a0 = *(short8*)&S_lds[w][lo][hi * 8];
            short8 a1 = *(short8*)&S_lds[w][lo][32 + hi * 8];
            #pragma unroll
            for (int ds = 0; ds < 4; ++ds) {
                short8 b0 = *(short8*)&V_lds[ds * 16 + lo][hi * 8];
                short8 b1 = *(short8*)&V_lds[ds * 16 + lo][32 + hi * 8];
                acc_o[ds] = __builtin_amdgcn_mfma_f32_16x16x32_bf16(a0, b0, acc_o[ds], 0, 0, 0);
                acc_o[ds] = __builtin_amdgcn_mfma_f32_16x16x32_bf16(a1, b1, acc_o[ds], 0, 0, 0);
            }
        }
        __syncthreads();

        #pragma unroll
        for (int sub = 0; sub < 4; ++sub)
            lvC[sub] = lvN[sub];
    }

    // epilogue: C[t=4hi+r][d=ds*16+lo]
    if (waveActive) {
        #pragma unroll
        for (int ds = 0; ds < 4; ++ds) {
            #pragma unroll
            for (int r = 0; r < 4; ++r) {
                const int tg = trow + 4 * hi + r;
                atomicAdd(&out[(size_t)tg * DQK + ds * 16 + lo], acc_o[ds][r]);
            }
        }
    }
}

extern "C" void kernel_launch(void* const* d_in, const int* in_sizes, int n_in,
                              void* d_out, int out_size, void* d_ws, size_t ws_size,
                              hipStream_t stream) {
    const float* x  = (const float*)d_in[0];
    const float* Wq = (const float*)d_in[1];
    const float* Wk = (const float*)d_in[2];
    const float* Wv = (const float*)d_in[3];
    const float* l  = (const float*)d_in[4];
    float* out = (float*)d_out;

    __hip_bfloat16* qb  = (__hip_bfloat16*)d_ws;
    __hip_bfloat16* kb  = qb + (size_t)TT * DQK;
    __hip_bfloat16* vt  = kb + (size_t)TT * DQK;
    __hip_bfloat16* wtb = vt + (size_t)TT * DQK;   // [3][64][512]

    init_kernel<<<48, 256, 0, stream>>>(Wq, Wk, Wv, wtb, out, out_size / 4);
    proj_kernel<<<TT / 64, 256, 0, stream>>>(x, wtb, qb, kb, vt);
    attn_kernel<<<dim3(TT / TM, TT / SCHUNK), 512, 0, stream>>>(qb, kb, vt, l, out);
}